// Round 19
// baseline (288.799 us; speedup 1.0000x reference)
//
#include <hip/hip_runtime.h>
#include <hip/hip_bf16.h>

#define SEQ 2048
#define LDQKV 6144

typedef __attribute__((ext_vector_type(8))) __bf16 bf16x8;
typedef __attribute__((ext_vector_type(4))) __bf16 bf16x4;
typedef __attribute__((ext_vector_type(4))) float f32x4;

__device__ __forceinline__ void gload_lds16(const void* g, void* l) {
  __builtin_amdgcn_global_load_lds((__attribute__((address_space(1))) void*)(g),
                                   (__attribute__((address_space(3))) void*)(l), 16, 0, 0);
}

// ---------------- all f32 -> bf16 conversions in one kernel (8 elems/thread) ----------------
struct CvtArgs {
  const float* src0; const float* src1; const float* src2; const float* src3; const float* src4;
  __bf16* dst0; __bf16* dst1; __bf16* dst2; __bf16* dst3; __bf16* dst4;
};
__global__ __launch_bounds__(256) void cvt_all(CvtArgs a) {
  int b = blockIdx.x;
  const float* s; __bf16* d; int boff;
  if (b < 4096)       { s = a.src0; d = a.dst0; boff = b; }
  else if (b < 12288) { s = a.src1; d = a.dst1; boff = b - 4096; }
  else if (b < 14336) { s = a.src2; d = a.dst2; boff = b - 12288; }
  else if (b < 16384) { s = a.src3; d = a.dst3; boff = b - 14336; }
  else                { s = a.src4; d = a.dst4; boff = b - 16384; }
  long i = ((long)boff * 256 + threadIdx.x) * 8;
  f32x4 v0 = *(const f32x4*)(s + i);
  f32x4 v1 = *(const f32x4*)(s + i + 4);
  bf16x8 o;
  #pragma unroll
  for (int j = 0; j < 4; ++j) { o[j] = (__bf16)v0[j]; o[j + 4] = (__bf16)v1[j]; }
  *(bf16x8*)(d + i) = o;
}

// ---------------- RoPE cos/sin table (reference fp16 inv_freq chain) ----------------
__global__ __launch_bounds__(256) void rope_tab_k(const int* __restrict__ pos,
                                                  float* __restrict__ tab) {
  int i = blockIdx.x * 256 + threadIdx.x;
  int s = i >> 6, j = i & 63;
  float p = (float)pos[s];
  float pw = powf(10000.0f, (float)j * (1.0f / 64.0f));
  _Float16 ph = (_Float16)pw;
  _Float16 ivh = (_Float16)(1.0f / (float)ph);
  float freq = (float)ivh;
  float th = p * freq;
  tab[i] = cosf(th);
  tab[SEQ * 64 + i] = sinf(th);
}

// ---------------- RoPE applied in-place to Q (32 heads) and K (8 heads) ----------------
__global__ __launch_bounds__(256) void rope_apply_k(__bf16* __restrict__ qkv,
                                                    const float* __restrict__ tab) {
  int i = blockIdx.x * 256 + threadIdx.x;
  int dc = i & 7;
  int ht = (i >> 3) % 40;
  int s = i / 320;
  long col = (ht < 32) ? (long)ht * 128 : (long)4096 + (long)(ht - 32) * 128;
  __bf16* p = qkv + (long)s * LDQKV + col + dc * 8;
  bf16x8 lo = *(bf16x8*)p;
  bf16x8 hi = *(bf16x8*)(p + 64);
  const float* tc = tab + (long)s * 64 + dc * 8;
  const float* ts = tc + SEQ * 64;
  bf16x8 lo2, hi2;
  #pragma unroll
  for (int e = 0; e < 8; ++e) {
    float c = tc[e], sn = ts[e];
    float lv = (float)lo[e], hv = (float)hi[e];
    lo2[e] = (__bf16)(lv * c - hv * sn);
    hi2[e] = (__bf16)(hv * c + lv * sn);
  }
  *(bf16x8*)p = lo2;
  *(bf16x8*)(p + 64) = hi2;
}

// ------- unified NT GEMM template; protocol selected at compile time per instantiation ------
// BUFS==2 (QKV, BN=384): verified 4-phase counted-vmcnt protocol (gemm8; 107 us in
//   rounds 12/14/17). Unit sizes A=1 load, B=3 loads -> vmcnt(4) counts identical.
// BUFS==3 (Wo, BN=256): verified whole-tile-publish deep-prefetch protocol (round-16/18;
//   ~84 us). Code path byte-identical to round 18 (compile-time branch).
template<int BN, int BUFS, bool OUT_BF16>
__global__ __launch_bounds__(512, 2) void gemmW(const __bf16* __restrict__ A,
                                                const __bf16* __restrict__ B,
                                                void* __restrict__ C,
                                                int K, int ldc) {
  constexpr int BHR = BN / 2;            // 192 | 128
  constexpr int NFR = BN / 128;          // 3 | 2
  constexpr int LB  = BHR / 64;          // 3 | 2
  constexpr int NA  = (BUFS == 3) ? 2 : 1;
  constexpr int TE  = (128 + BN) * 64;   // tile elems: 32768 | 24576
  extern __shared__ __bf16 lds[];

  const int tid = threadIdx.x;
  const int wave = tid >> 6, lane = tid & 63;
  const int l15 = lane & 15, l4 = lane >> 4;
  const int wm = wave >> 2, wn = wave & 3;

  const int orig = blockIdx.x;           // XCD-bijective swizzle (256 % 8 == 0)
  const int swz = (orig & 7) * 32 + (orig >> 3);
  const int bx = swz & 15, by = swz >> 4;
  const long brow = (long)bx * 128, bcol = (long)by * BN;

  const int rS = tid >> 3;
  const int cS = ((tid & 7) * 8) ^ ((rS & 7) << 3);
  const int NT = K >> 6;

  auto bufp = [&](int b) -> __bf16* { return lds + b * TE; };
  auto stageA = [&](int b, int qm, int t) {
    gload_lds16(A + (brow + qm * 64 + rS) * (long)K + t * 64 + cS,
                bufp(b) + qm * 4096 + wave * 512);
  };
  auto stageB = [&](int b, int qn, int t) {
    #pragma unroll
    for (int i = 0; i < LB; ++i)
      gload_lds16(B + (bcol + qn * BHR + i * 64 + rS) * (long)K + t * 64 + cS,
                  bufp(b) + 8192 + qn * (BHR * 64) + i * 4096 + wave * 512);
  };

  bf16x8 afLo[2][2], afHi[2][2], b0[NFR][2], b1[NFR][2];
  auto readA = [&](bf16x8 (&dst)[2][2], int b, int qm) {
    #pragma unroll
    for (int mi = 0; mi < 2; ++mi) {
      int r = wm * 32 + mi * 16 + l15;
      #pragma unroll
      for (int kf = 0; kf < 2; ++kf) {
        int c = (kf * 32 + l4 * 8) ^ ((r & 7) << 3);
        dst[mi][kf] = *(const bf16x8*)&bufp(b)[qm * 4096 + r * 64 + c];
      }
    }
  };
  auto readB = [&](bf16x8 (&dst)[NFR][2], int b, int qn) {
    #pragma unroll
    for (int ni = 0; ni < NFR; ++ni) {
      int r = wn * (BN / 8) + ni * 16 + l15;
      #pragma unroll
      for (int kf = 0; kf < 2; ++kf) {
        int c = (kf * 32 + l4 * 8) ^ ((r & 7) << 3);
        dst[ni][kf] = *(const bf16x8*)&bufp(b)[8192 + qn * (BHR * 64) + r * 64 + c];
      }
    }
  };

  f32x4 acc[2][2][2][NFR] = {};   // [qm][qn][mi][ni]
  auto mfmaQ = [&](bf16x8 (&af)[2][2], bf16x8 (&bf_)[NFR][2], f32x4 (&ac)[2][NFR]) {
    __builtin_amdgcn_s_setprio(1);
    #pragma unroll
    for (int mi = 0; mi < 2; ++mi)
      #pragma unroll
      for (int ni = 0; ni < NFR; ++ni)
        #pragma unroll
        for (int kf = 0; kf < 2; ++kf)
          ac[mi][ni] = __builtin_amdgcn_mfma_f32_16x16x32_bf16(af[mi][kf], bf_[ni][kf], ac[mi][ni], 0, 0, 0);
    __builtin_amdgcn_s_setprio(0);
  };

  if constexpr (BUFS == 2) {
    // ---------- 4-phase counted-vmcnt protocol (gemm8 transcription) ----------
    #define VM_WAIT4() asm volatile("s_waitcnt vmcnt(4)" ::: "memory")
    #define PH_BAR()   do { __builtin_amdgcn_s_barrier(); __builtin_amdgcn_sched_barrier(0); } while (0)
    stageA(0, 0, 0); stageB(0, 0, 0); stageA(0, 1, 0); stageB(0, 1, 0);
    VM_WAIT4();
    PH_BAR();
    for (int t = 0; t < NT; ++t) {
      const int buf = t & 1, nb = buf ^ 1;
      const bool pf = (t + 1 < NT);
      // ph0: Q00; stage A0(t+1); reads A0 + B0
      if (pf) stageA(nb, 0, t + 1);
      readA(afLo, buf, 0); readB(b0, buf, 0);
      mfmaQ(afLo, b0, acc[0][0]);
      VM_WAIT4();
      PH_BAR();
      // ph1: Q10; stage B0(t+1); reads A1
      if (pf) stageB(nb, 0, t + 1);
      readA(afHi, buf, 1);
      mfmaQ(afHi, b0, acc[1][0]);
      VM_WAIT4();
      PH_BAR();
      // ph2: Q11; stage A1(t+1); reads B1
      if (pf) stageA(nb, 1, t + 1);
      readB(b1, buf, 1);
      mfmaQ(afHi, b1, acc[1][1]);
      PH_BAR();
      // ph3: Q01; stage B1(t+1); zero reads (afLo, b1 held)
      if (pf) stageB(nb, 1, t + 1);
      mfmaQ(afLo, b1, acc[0][1]);
      VM_WAIT4();
      PH_BAR();
    }
    #undef VM_WAIT4
    #undef PH_BAR
  } else {
    // ---------- whole-tile-publish deep-prefetch protocol (round-16/18, unchanged) ----------
    #pragma unroll
    for (int tt = 0; tt < NA; ++tt) {
      stageA(tt % BUFS, 0, tt); stageB(tt % BUFS, 0, tt);
      stageA(tt % BUFS, 1, tt); stageB(tt % BUFS, 1, tt);
    }
    asm volatile("s_waitcnt vmcnt(6)" ::: "memory");
    __builtin_amdgcn_s_barrier();
    __builtin_amdgcn_sched_barrier(0);

    for (int t = 0; t < NT; ++t) {
      const int cur = t % BUFS, pre = (t + NA) % BUFS;
      const bool pf = (t + NA < NT);
      readA(afLo, cur, 0); readB(b0, cur, 0);
      if (pf) { stageA(pre, 0, t + NA); stageB(pre, 0, t + NA); }
      mfmaQ(afLo, b0, acc[0][0]);
      readA(afHi, cur, 1); readB(b1, cur, 1);
      if (pf) { stageA(pre, 1, t + NA); stageB(pre, 1, t + NA); }
      mfmaQ(afHi, b0, acc[1][0]);
      mfmaQ(afHi, b1, acc[1][1]);
      mfmaQ(afLo, b1, acc[0][1]);
      if (t + 1 < NT) {
        __builtin_amdgcn_sched_barrier(0);
        if (pf) asm volatile("s_waitcnt vmcnt(6)" ::: "memory");
        else    asm volatile("s_waitcnt vmcnt(0)" ::: "memory");
        __builtin_amdgcn_s_barrier();
        __builtin_amdgcn_sched_barrier(0);
      }
    }
  }

  #pragma unroll
  for (int qm = 0; qm < 2; ++qm)
    #pragma unroll
    for (int qn = 0; qn < 2; ++qn)
      #pragma unroll
      for (int mi = 0; mi < 2; ++mi)
        #pragma unroll
        for (int ni = 0; ni < NFR; ++ni)
          #pragma unroll
          for (int j = 0; j < 4; ++j) {
            long rr = brow + qm * 64 + wm * 32 + mi * 16 + l4 * 4 + j;
            long cc = bcol + qn * BHR + wn * (BN / 8) + ni * 16 + l15;
            float v = acc[qm][qn][mi][ni][j];
            if (OUT_BF16) ((__bf16*)C)[rr * ldc + cc] = (__bf16)v;
            else          ((float*)C)[rr * ldc + cc] = v;
          }
}

// ---------------- flash attention v3b (causal, GQA 4:1) ---------------- (unchanged)
__global__ __launch_bounds__(256) void flash_k(const __bf16* __restrict__ qkv,
                                               __bf16* __restrict__ ctx) {
  __shared__ __align__(16) __bf16 Kl[8192];
  __shared__ __align__(16) __bf16 Vt[8192];
  __shared__ __align__(16) __bf16 Pl[4][1024];

  const int bid = blockIdx.x;
  const int h = bid & 31;
  const int qt = 31 - (bid >> 5);
  const int kvh = h >> 2;
  const int q0 = qt * 64;
  const int tid = threadIdx.x, wave = tid >> 6, lane = tid & 63;
  const int l15 = lane & 15, l4 = lane >> 4;
  const int d2 = tid & 63, grp = tid >> 6;

  const __bf16* Qp = qkv + (long)h * 128;
  const __bf16* Kp = qkv + 4096 + (long)kvh * 128;
  const __bf16* Vp = qkv + 5120 + (long)kvh * 128;

  bf16x8 aq[4];
  {
    long qr = q0 + wave * 16 + l15;
    #pragma unroll
    for (int ks = 0; ks < 4; ++ks)
      aq[ks] = *(const bf16x8*)(Qp + qr * LDQKV + ks * 32 + l4 * 8);
  }
  f32x4 accO[8] = {};
  float lsum[4] = {0.f, 0.f, 0.f, 0.f};
  const float cexp = 0.08838834764831845f * 1.4426950408889634f;

  for (int kv0 = 0; kv0 <= q0; kv0 += 64) {
    __syncthreads();
    #pragma unroll
    for (int i = 0; i < 4; ++i) {
      int fo = i * 2048 + wave * 512 + lane * 8;
      int r = fo >> 7, c = fo & 127;
      int cs = c ^ ((r & 7) << 3);
      gload_lds16(Kp + (long)(kv0 + r) * LDQKV + cs, &Kl[i * 2048 + wave * 512]);
    }
    unsigned int vv[2][8];
    #pragma unroll
    for (int rep = 0; rep < 2; ++rep) {
      int cch = grp * 2 + rep;
      #pragma unroll
      for (int i = 0; i < 8; ++i)
        vv[rep][i] = *(const unsigned int*)(Vp + (long)(kv0 + cch * 8 + i) * LDQKV + 2 * d2);
    }
    #pragma unroll
    for (int rep = 0; rep < 2; ++rep) {
      int cch = grp * 2 + rep;
      #pragma unroll
      for (int half = 0; half < 2; ++half) {
        bf16x8 w;
        #pragma unroll
        for (int i = 0; i < 8; ++i)
          w[i] = __builtin_bit_cast(__bf16, (unsigned short)(vv[rep][i] >> (16 * half)));
        int d = 2 * d2 + half;
        *(bf16x8*)&Vt[d * 64 + ((cch * 8) ^ ((d2 & 7) * 8))] = w;
      }
    }
    __syncthreads();

    f32x4 s[4];
    #pragma unroll
    for (int t = 0; t < 4; ++t) s[t] = f32x4{0.f, 0.f, 0.f, 0.f};
    __builtin_amdgcn_s_setprio(1);
    #pragma unroll
    for (int t = 0; t < 4; ++t) {
      int r = t * 16 + l15;
      #pragma unroll
      for (int ks = 0; ks < 4; ++ks) {
        bf16x8 bk = *(const bf16x8*)&Kl[r * 128 + ((ks * 32 + l4 * 8) ^ ((r & 7) << 3))];
        s[t] = __builtin_amdgcn_mfma_f32_16x16x32_bf16(aq[ks], bk, s[t], 0, 0, 0);
      }
    }
    __builtin_amdgcn_s_setprio(0);

    const bool lastStep = (kv0 == q0);
    float pout[4][4];
    #pragma unroll
    for (int t = 0; t < 4; ++t)
      #pragma unroll
      for (int j = 0; j < 4; ++j) {
        float p = exp2f(s[t][j] * cexp);
        if (lastStep) {
          int qg = wave * 16 + l4 * 4 + j;
          int kg = t * 16 + l15;
          if (kg > qg) p = 0.f;
        }
        pout[t][j] = p;
      }
    #pragma unroll
    for (int j = 0; j < 4; ++j)
      lsum[j] += (pout[0][j] + pout[1][j]) + (pout[2][j] + pout[3][j]);

    #pragma unroll
    for (int t = 0; t < 4; ++t)
      #pragma unroll
      for (int j = 0; j < 4; ++j) {
        int r = l4 * 4 + j;
        int c = t * 16 + l15;
        Pl[wave][r * 64 + (c ^ ((r & 7) << 3))] = (__bf16)pout[t][j];
      }
    asm volatile("s_waitcnt lgkmcnt(0)" ::: "memory");
    __builtin_amdgcn_sched_barrier(0);
    bf16x8 ap[2];
    #pragma unroll
    for (int ks2 = 0; ks2 < 2; ++ks2) {
      int c = ks2 * 32 + l4 * 8;
      ap[ks2] = *(const bf16x8*)&Pl[wave][l15 * 64 + (c ^ ((l15 & 7) << 3))];
    }
    __builtin_amdgcn_s_setprio(1);
    #pragma unroll
    for (int dt = 0; dt < 8; ++dt) {
      int d = dt * 16 + l15;
      #pragma unroll
      for (int ks2 = 0; ks2 < 2; ++ks2) {
        int c = (ks2 * 32 + l4 * 8) ^ (((l15 >> 1) & 7) * 8);
        bf16x8 bv = *(const bf16x8*)&Vt[d * 64 + c];
        accO[dt] = __builtin_amdgcn_mfma_f32_16x16x32_bf16(ap[ks2], bv, accO[dt], 0, 0, 0);
      }
    }
    __builtin_amdgcn_s_setprio(0);
  }
  float rls[4];
  #pragma unroll
  for (int j = 0; j < 4; ++j) {
    float ls = lsum[j];
    ls += __shfl_xor(ls, 1, 16);
    ls += __shfl_xor(ls, 2, 16);
    ls += __shfl_xor(ls, 4, 16);
    ls += __shfl_xor(ls, 8, 16);
    rls[j] = 1.f / ls;
  }
  #pragma unroll
  for (int dt = 0; dt < 8; ++dt)
    #pragma unroll
    for (int j = 0; j < 4; ++j) {
      long qr = q0 + wave * 16 + l4 * 4 + j;
      long cc = (long)h * 128 + dt * 16 + l15;
      ctx[qr * 4096 + cc] = (__bf16)(accO[dt][j] * rls[j]);
    }
}

// ---------------- launch ----------------
extern "C" void kernel_launch(void* const* d_in, const int* in_sizes, int n_in,
                              void* d_out, int out_size, void* d_ws, size_t ws_size,
                              hipStream_t stream) {
  const float* hs  = (const float*)d_in[0];
  const int*   pos = (const int*)d_in[2];
  const float* Wq  = (const float*)d_in[3];
  const float* Wk  = (const float*)d_in[4];
  const float* Wv  = (const float*)d_in[5];
  const float* Wo  = (const float*)d_in[6];
  char* ws = (char*)d_ws;
  __bf16* hsb  = (__bf16*)(ws + 0L);
  __bf16* wqkv = (__bf16*)(ws + 16777216L);
  __bf16* wob  = (__bf16*)(ws + 67108864L);
  __bf16* qkvb = (__bf16*)(ws + 100663296L);
  float*  tab  = (float*)(ws + 125829120L);
  __bf16* ctx  = (__bf16*)(ws + 126877696L);

  (void)hipFuncSetAttribute(reinterpret_cast<const void*>(&gemmW<384, 2, true>),
                            hipFuncAttributeMaxDynamicSharedMemorySize, 131072);
  (void)hipFuncSetAttribute(reinterpret_cast<const void*>(&gemmW<256, 3, false>),
                            hipFuncAttributeMaxDynamicSharedMemorySize, 147456);

  CvtArgs ca;
  ca.src0 = hs;  ca.dst0 = hsb;
  ca.src1 = Wq;  ca.dst1 = wqkv;
  ca.src2 = Wk;  ca.dst2 = wqkv + 16777216L;
  ca.src3 = Wv;  ca.dst3 = wqkv + 20971520L;
  ca.src4 = Wo;  ca.dst4 = wob;
  cvt_all<<<24576, 256, 0, stream>>>(ca);
  rope_tab_k<<<512, 256, 0, stream>>>(pos, tab);

  gemmW<384, 2, true><<<256, 512, 131072, stream>>>(hsb, wqkv, qkvb, 4096, 6144);

  rope_apply_k<<<2560, 256, 0, stream>>>(qkvb, tab);

  flash_k<<<1024, 256, 0, stream>>>(qkvb, ctx);

  gemmW<256, 3, false><<<256, 512, 147456, stream>>>(ctx, wob, d_out, 4096, 4096);
}

// Round 20
// 282.546 us; speedup vs baseline: 1.0221x; 1.0221x over previous
//
#include <hip/hip_runtime.h>
#include <hip/hip_bf16.h>

#define SEQ 2048
#define LDQKV 6144

typedef __attribute__((ext_vector_type(8))) __bf16 bf16x8;
typedef __attribute__((ext_vector_type(4))) __bf16 bf16x4;
typedef __attribute__((ext_vector_type(4))) float f32x4;

__device__ __forceinline__ void gload_lds16(const void* g, void* l) {
  __builtin_amdgcn_global_load_lds((__attribute__((address_space(1))) void*)(g),
                                   (__attribute__((address_space(3))) void*)(l), 16, 0, 0);
}

// ---------------- all f32 -> bf16 conversions in one kernel (8 elems/thread) ----------------
struct CvtArgs {
  const float* src0; const float* src1; const float* src2; const float* src3; const float* src4;
  __bf16* dst0; __bf16* dst1; __bf16* dst2; __bf16* dst3; __bf16* dst4;
};
__global__ __launch_bounds__(256) void cvt_all(CvtArgs a) {
  int b = blockIdx.x;
  const float* s; __bf16* d; int boff;
  if (b < 4096)       { s = a.src0; d = a.dst0; boff = b; }
  else if (b < 12288) { s = a.src1; d = a.dst1; boff = b - 4096; }
  else if (b < 14336) { s = a.src2; d = a.dst2; boff = b - 12288; }
  else if (b < 16384) { s = a.src3; d = a.dst3; boff = b - 14336; }
  else                { s = a.src4; d = a.dst4; boff = b - 16384; }
  long i = ((long)boff * 256 + threadIdx.x) * 8;
  f32x4 v0 = *(const f32x4*)(s + i);
  f32x4 v1 = *(const f32x4*)(s + i + 4);
  bf16x8 o;
  #pragma unroll
  for (int j = 0; j < 4; ++j) { o[j] = (__bf16)v0[j]; o[j + 4] = (__bf16)v1[j]; }
  *(bf16x8*)(d + i) = o;
}

// ---------------- RoPE cos/sin table (reference fp16 inv_freq chain) ----------------
__global__ __launch_bounds__(256) void rope_tab_k(const int* __restrict__ pos,
                                                  float* __restrict__ tab) {
  int i = blockIdx.x * 256 + threadIdx.x;
  int s = i >> 6, j = i & 63;
  float p = (float)pos[s];
  float pw = powf(10000.0f, (float)j * (1.0f / 64.0f));
  _Float16 ph = (_Float16)pw;
  _Float16 ivh = (_Float16)(1.0f / (float)ph);
  float freq = (float)ivh;
  float th = p * freq;
  tab[i] = cosf(th);
  tab[SEQ * 64 + i] = sinf(th);
}

// ---------------- RoPE applied in-place to Q (32 heads) and K (8 heads) ----------------
__global__ __launch_bounds__(256) void rope_apply_k(__bf16* __restrict__ qkv,
                                                    const float* __restrict__ tab) {
  int i = blockIdx.x * 256 + threadIdx.x;
  int dc = i & 7;
  int ht = (i >> 3) % 40;
  int s = i / 320;
  long col = (ht < 32) ? (long)ht * 128 : (long)4096 + (long)(ht - 32) * 128;
  __bf16* p = qkv + (long)s * LDQKV + col + dc * 8;
  bf16x8 lo = *(bf16x8*)p;
  bf16x8 hi = *(bf16x8*)(p + 64);
  const float* tc = tab + (long)s * 64 + dc * 8;
  const float* ts = tc + SEQ * 64;
  bf16x8 lo2, hi2;
  #pragma unroll
  for (int e = 0; e < 8; ++e) {
    float c = tc[e], sn = ts[e];
    float lv = (float)lo[e], hv = (float)hi[e];
    lo2[e] = (__bf16)(lv * c - hv * sn);
    hi2[e] = (__bf16)(hv * c + lv * sn);
  }
  *(bf16x8*)p = lo2;
  *(bf16x8*)(p + 64) = hi2;
}

// ------- whole-tile-publish NT GEMM: ONE barrier/tile, barrier-free tile body -------
// BM=128, BN=384|256 -> grid 16x16 = 256 = 1/CU, 512 thr / 8 waves (2M x 4N), BK=64.
// Whole tile published at one pinned barrier; inside a tile NO barriers / NO lgkm pins --
// ds_reads issue in two clusters and counted compiler lgkm gates let MFMAs stream.
// QKV: BUFS=2 (128 KB), stage t+1, tile-end vmcnt(0).
// Wo : BUFS=3 (144 KB), stage t+2, tile-end vmcnt(6).
template<int BN, int BUFS, bool OUT_BF16>
__global__ __launch_bounds__(512, 2) void gemmW(const __bf16* __restrict__ A,
                                                const __bf16* __restrict__ B,
                                                void* __restrict__ C,
                                                int K, int ldc) {
  constexpr int BHR = BN / 2;            // 192 | 128
  constexpr int NFR = BN / 128;          // 3 | 2
  constexpr int LB  = BHR / 64;          // 3 | 2
  constexpr int NA  = (BUFS == 3) ? 2 : 1;
  constexpr int TE  = (128 + BN) * 64;   // tile elems: 32768 | 24576
  extern __shared__ __bf16 lds[];

  const int tid = threadIdx.x;
  const int wave = tid >> 6, lane = tid & 63;
  const int l15 = lane & 15, l4 = lane >> 4;
  const int wm = wave >> 2, wn = wave & 3;

  const int orig = blockIdx.x;           // XCD-bijective swizzle (256 % 8 == 0)
  const int swz = (orig & 7) * 32 + (orig >> 3);
  const int bx = swz & 15, by = swz >> 4;
  const long brow = (long)bx * 128, bcol = (long)by * BN;

  const int rS = tid >> 3;
  const int cS = ((tid & 7) * 8) ^ ((rS & 7) << 3);
  const int NT = K >> 6;

  auto bufp = [&](int b) -> __bf16* { return lds + b * TE; };
  auto stageA = [&](int b, int qm, int t) {
    gload_lds16(A + (brow + qm * 64 + rS) * (long)K + t * 64 + cS,
                bufp(b) + qm * 4096 + wave * 512);
  };
  auto stageB = [&](int b, int qn, int t) {
    #pragma unroll
    for (int i = 0; i < LB; ++i)
      gload_lds16(B + (bcol + qn * BHR + i * 64 + rS) * (long)K + t * 64 + cS,
                  bufp(b) + 8192 + qn * (BHR * 64) + i * 4096 + wave * 512);
  };

  bf16x8 afLo[2][2], afHi[2][2], b0[NFR][2], b1[NFR][2];
  auto readA = [&](bf16x8 (&dst)[2][2], int b, int qm) {
    #pragma unroll
    for (int mi = 0; mi < 2; ++mi) {
      int r = wm * 32 + mi * 16 + l15;
      #pragma unroll
      for (int kf = 0; kf < 2; ++kf) {
        int c = (kf * 32 + l4 * 8) ^ ((r & 7) << 3);
        dst[mi][kf] = *(const bf16x8*)&bufp(b)[qm * 4096 + r * 64 + c];
      }
    }
  };
  auto readB = [&](bf16x8 (&dst)[NFR][2], int b, int qn) {
    #pragma unroll
    for (int ni = 0; ni < NFR; ++ni) {
      int r = wn * (BN / 8) + ni * 16 + l15;
      #pragma unroll
      for (int kf = 0; kf < 2; ++kf) {
        int c = (kf * 32 + l4 * 8) ^ ((r & 7) << 3);
        dst[ni][kf] = *(const bf16x8*)&bufp(b)[8192 + qn * (BHR * 64) + r * 64 + c];
      }
    }
  };

  f32x4 acc[2][2][2][NFR] = {};   // [qm][qn][mi][ni]
  auto mfmaQ = [&](bf16x8 (&af)[2][2], bf16x8 (&bf_)[NFR][2], f32x4 (&ac)[2][NFR]) {
    __builtin_amdgcn_s_setprio(1);
    #pragma unroll
    for (int mi = 0; mi < 2; ++mi)
      #pragma unroll
      for (int ni = 0; ni < NFR; ++ni)
        #pragma unroll
        for (int kf = 0; kf < 2; ++kf)
          ac[mi][ni] = __builtin_amdgcn_mfma_f32_16x16x32_bf16(af[mi][kf], bf_[ni][kf], ac[mi][ni], 0, 0, 0);
    __builtin_amdgcn_s_setprio(0);
  };

  // prologue: stage first NA tiles; land all but the newest tile's units; publish
  #pragma unroll
  for (int tt = 0; tt < NA; ++tt) {
    stageA(tt % BUFS, 0, tt); stageB(tt % BUFS, 0, tt);
    stageA(tt % BUFS, 1, tt); stageB(tt % BUFS, 1, tt);
  }
  if constexpr (BUFS == 3) asm volatile("s_waitcnt vmcnt(6)" ::: "memory");
  else                     asm volatile("s_waitcnt vmcnt(0)" ::: "memory");
  __builtin_amdgcn_s_barrier();
  __builtin_amdgcn_sched_barrier(0);

  for (int t = 0; t < NT; ++t) {
    const int cur = t % BUFS, pre = (t + NA) % BUFS;
    const bool pf = (t + NA < NT);
    // cluster 1: reads for Q00 row/col sets; stage first half of tile t+NA
    readA(afLo, cur, 0); readB(b0, cur, 0);
    if (pf) { stageA(pre, 0, t + NA); stageB(pre, 0, t + NA); }
    mfmaQ(afLo, b0, acc[0][0]);
    // cluster 2: remaining reads; stage second half
    readA(afHi, cur, 1); readB(b1, cur, 1);
    if (pf) { stageA(pre, 1, t + NA); stageB(pre, 1, t + NA); }
    mfmaQ(afHi, b0, acc[1][0]);
    mfmaQ(afHi, b1, acc[1][1]);
    mfmaQ(afLo, b1, acc[0][1]);
    // tile end: single pinned publish barrier
    if (t + 1 < NT) {
      __builtin_amdgcn_sched_barrier(0);
      if constexpr (BUFS == 3) {
        if (pf) asm volatile("s_waitcnt vmcnt(6)" ::: "memory");
        else    asm volatile("s_waitcnt vmcnt(0)" ::: "memory");
      } else {
        asm volatile("s_waitcnt vmcnt(0)" ::: "memory");
      }
      __builtin_amdgcn_s_barrier();
      __builtin_amdgcn_sched_barrier(0);
    }
  }

  #pragma unroll
  for (int qm = 0; qm < 2; ++qm)
    #pragma unroll
    for (int qn = 0; qn < 2; ++qn)
      #pragma unroll
      for (int mi = 0; mi < 2; ++mi)
        #pragma unroll
        for (int ni = 0; ni < NFR; ++ni)
          #pragma unroll
          for (int j = 0; j < 4; ++j) {
            long rr = brow + qm * 64 + wm * 32 + mi * 16 + l4 * 4 + j;
            long cc = bcol + qn * BHR + wn * (BN / 8) + ni * 16 + l15;
            float v = acc[qm][qn][mi][ni][j];
            if (OUT_BF16) ((__bf16*)C)[rr * ldc + cc] = (__bf16)v;
            else          ((float*)C)[rr * ldc + cc] = v;
          }
}

// ---------------- flash attention v3b (causal, GQA 4:1) ----------------
__global__ __launch_bounds__(256) void flash_k(const __bf16* __restrict__ qkv,
                                               __bf16* __restrict__ ctx) {
  __shared__ __align__(16) __bf16 Kl[8192];
  __shared__ __align__(16) __bf16 Vt[8192];
  __shared__ __align__(16) __bf16 Pl[4][1024];

  const int bid = blockIdx.x;
  const int h = bid & 31;
  const int qt = 31 - (bid >> 5);
  const int kvh = h >> 2;
  const int q0 = qt * 64;
  const int tid = threadIdx.x, wave = tid >> 6, lane = tid & 63;
  const int l15 = lane & 15, l4 = lane >> 4;
  const int d2 = tid & 63, grp = tid >> 6;

  const __bf16* Qp = qkv + (long)h * 128;
  const __bf16* Kp = qkv + 4096 + (long)kvh * 128;
  const __bf16* Vp = qkv + 5120 + (long)kvh * 128;

  bf16x8 aq[4];
  {
    long qr = q0 + wave * 16 + l15;
    #pragma unroll
    for (int ks = 0; ks < 4; ++ks)
      aq[ks] = *(const bf16x8*)(Qp + qr * LDQKV + ks * 32 + l4 * 8);
  }
  f32x4 accO[8] = {};
  float lsum[4] = {0.f, 0.f, 0.f, 0.f};
  const float cexp = 0.08838834764831845f * 1.4426950408889634f;

  for (int kv0 = 0; kv0 <= q0; kv0 += 64) {
    __syncthreads();
    #pragma unroll
    for (int i = 0; i < 4; ++i) {
      int fo = i * 2048 + wave * 512 + lane * 8;
      int r = fo >> 7, c = fo & 127;
      int cs = c ^ ((r & 7) << 3);
      gload_lds16(Kp + (long)(kv0 + r) * LDQKV + cs, &Kl[i * 2048 + wave * 512]);
    }
    unsigned int vv[2][8];
    #pragma unroll
    for (int rep = 0; rep < 2; ++rep) {
      int cch = grp * 2 + rep;
      #pragma unroll
      for (int i = 0; i < 8; ++i)
        vv[rep][i] = *(const unsigned int*)(Vp + (long)(kv0 + cch * 8 + i) * LDQKV + 2 * d2);
    }
    #pragma unroll
    for (int rep = 0; rep < 2; ++rep) {
      int cch = grp * 2 + rep;
      #pragma unroll
      for (int half = 0; half < 2; ++half) {
        bf16x8 w;
        #pragma unroll
        for (int i = 0; i < 8; ++i)
          w[i] = __builtin_bit_cast(__bf16, (unsigned short)(vv[rep][i] >> (16 * half)));
        int d = 2 * d2 + half;
        *(bf16x8*)&Vt[d * 64 + ((cch * 8) ^ ((d2 & 7) * 8))] = w;
      }
    }
    __syncthreads();

    f32x4 s[4];
    #pragma unroll
    for (int t = 0; t < 4; ++t) s[t] = f32x4{0.f, 0.f, 0.f, 0.f};
    __builtin_amdgcn_s_setprio(1);
    #pragma unroll
    for (int t = 0; t < 4; ++t) {
      int r = t * 16 + l15;
      #pragma unroll
      for (int ks = 0; ks < 4; ++ks) {
        bf16x8 bk = *(const bf16x8*)&Kl[r * 128 + ((ks * 32 + l4 * 8) ^ ((r & 7) << 3))];
        s[t] = __builtin_amdgcn_mfma_f32_16x16x32_bf16(aq[ks], bk, s[t], 0, 0, 0);
      }
    }
    __builtin_amdgcn_s_setprio(0);

    const bool lastStep = (kv0 == q0);
    float pout[4][4];
    #pragma unroll
    for (int t = 0; t < 4; ++t)
      #pragma unroll
      for (int j = 0; j < 4; ++j) {
        float p = exp2f(s[t][j] * cexp);
        if (lastStep) {
          int qg = wave * 16 + l4 * 4 + j;
          int kg = t * 16 + l15;
          if (kg > qg) p = 0.f;
        }
        pout[t][j] = p;
      }
    #pragma unroll
    for (int j = 0; j < 4; ++j)
      lsum[j] += (pout[0][j] + pout[1][j]) + (pout[2][j] + pout[3][j]);

    #pragma unroll
    for (int t = 0; t < 4; ++t)
      #pragma unroll
      for (int j = 0; j < 4; ++j) {
        int r = l4 * 4 + j;
        int c = t * 16 + l15;
        Pl[wave][r * 64 + (c ^ ((r & 7) << 3))] = (__bf16)pout[t][j];
      }
    asm volatile("s_waitcnt lgkmcnt(0)" ::: "memory");
    __builtin_amdgcn_sched_barrier(0);
    bf16x8 ap[2];
    #pragma unroll
    for (int ks2 = 0; ks2 < 2; ++ks2) {
      int c = ks2 * 32 + l4 * 8;
      ap[ks2] = *(const bf16x8*)&Pl[wave][l15 * 64 + (c ^ ((l15 & 7) << 3))];
    }
    __builtin_amdgcn_s_setprio(1);
    #pragma unroll
    for (int dt = 0; dt < 8; ++dt) {
      int d = dt * 16 + l15;
      #pragma unroll
      for (int ks2 = 0; ks2 < 2; ++ks2) {
        int c = (ks2 * 32 + l4 * 8) ^ (((l15 >> 1) & 7) * 8);
        bf16x8 bv = *(const bf16x8*)&Vt[d * 64 + c];
        accO[dt] = __builtin_amdgcn_mfma_f32_16x16x32_bf16(ap[ks2], bv, accO[dt], 0, 0, 0);
      }
    }
    __builtin_amdgcn_s_setprio(0);
  }
  float rls[4];
  #pragma unroll
  for (int j = 0; j < 4; ++j) {
    float ls = lsum[j];
    ls += __shfl_xor(ls, 1, 16);
    ls += __shfl_xor(ls, 2, 16);
    ls += __shfl_xor(ls, 4, 16);
    ls += __shfl_xor(ls, 8, 16);
    rls[j] = 1.f / ls;
  }
  #pragma unroll
  for (int dt = 0; dt < 8; ++dt)
    #pragma unroll
    for (int j = 0; j < 4; ++j) {
      long qr = q0 + wave * 16 + l4 * 4 + j;
      long cc = (long)h * 128 + dt * 16 + l15;
      ctx[qr * 4096 + cc] = (__bf16)(accO[dt][j] * rls[j]);
    }
}

// ---------------- launch ----------------
extern "C" void kernel_launch(void* const* d_in, const int* in_sizes, int n_in,
                              void* d_out, int out_size, void* d_ws, size_t ws_size,
                              hipStream_t stream) {
  const float* hs  = (const float*)d_in[0];
  const int*   pos = (const int*)d_in[2];
  const float* Wq  = (const float*)d_in[3];
  const float* Wk  = (const float*)d_in[4];
  const float* Wv  = (const float*)d_in[5];
  const float* Wo  = (const float*)d_in[6];
  char* ws = (char*)d_ws;
  __bf16* hsb  = (__bf16*)(ws + 0L);
  __bf16* wqkv = (__bf16*)(ws + 16777216L);
  __bf16* wob  = (__bf16*)(ws + 67108864L);
  __bf16* qkvb = (__bf16*)(ws + 100663296L);
  float*  tab  = (float*)(ws + 125829120L);
  __bf16* ctx  = (__bf16*)(ws + 126877696L);

  (void)hipFuncSetAttribute(reinterpret_cast<const void*>(&gemmW<384, 2, true>),
                            hipFuncAttributeMaxDynamicSharedMemorySize, 131072);
  (void)hipFuncSetAttribute(reinterpret_cast<const void*>(&gemmW<256, 3, false>),
                            hipFuncAttributeMaxDynamicSharedMemorySize, 147456);

  CvtArgs ca;
  ca.src0 = hs;  ca.dst0 = hsb;
  ca.src1 = Wq;  ca.dst1 = wqkv;
  ca.src2 = Wk;  ca.dst2 = wqkv + 16777216L;
  ca.src3 = Wv;  ca.dst3 = wqkv + 20971520L;
  ca.src4 = Wo;  ca.dst4 = wob;
  cvt_all<<<24576, 256, 0, stream>>>(ca);
  rope_tab_k<<<512, 256, 0, stream>>>(pos, tab);

  gemmW<384, 2, true><<<256, 512, 131072, stream>>>(hsb, wqkv, qkvb, 4096, 6144);

  rope_apply_k<<<2560, 256, 0, stream>>>(qkvb, tab);

  flash_k<<<1024, 256, 0, stream>>>(qkvb, ctx);

  gemmW<256, 3, false><<<256, 512, 147456, stream>>>(ctx, wob, d_out, 4096, 4096);
}